// Round 21
// baseline (53.104 us; speedup 1.0000x reference)
//
#include <hip/hip_runtime.h>

#define N_NODES 50000
#define N_EDGES 800000
#define D_IN 256
#define D_OUT 64
#define NEG_SLOPE 0.2f

#define GEMM_BLOCKS 782    // ceil(50000/64) — dispatched FIRST (long poles)
#define PREP2_BLOCKS 3125  // ceil(800000/256) — 1 edge/thread, appended
#define GRID1 (GEMM_BLOCKS + PREP2_BLOCKS)

typedef __attribute__((ext_vector_type(8))) short bf16x8;   // 8 bf16 = 4 VGPR
typedef __attribute__((ext_vector_type(4))) float f32x4;    // MFMA C/D
typedef __attribute__((ext_vector_type(4))) int   i32x4;

__device__ inline ushort f2bf(float f) {  // f32 -> bf16, round-nearest-even
  union { float f; unsigned u; } v; v.f = f;
  unsigned r = v.u + 0x7FFFu + ((v.u >> 16) & 1u);
  return (ushort)(r >> 16);
}
__device__ inline float bf2f(ushort h) {
  union { unsigned u; float f; } v; v.u = ((unsigned)h) << 16;
  return v.f;
}

// Issue one 16B global load via asm volatile (R12, kept).
#define XLOAD(dst, off)                                                  \
  asm volatile("global_load_dwordx4 %0, %1, off offset:" #off            \
               : "=v"(dst) : "v"(xp) : "memory")

// ---------------------------------------------------------------------------
// Kernel 1 — EXACT R18/R20 (frozen). blocks <782 = one 16x64 MFMA tile per
// wave; blocks >=782 = CSR row_ptr, one edge per thread.
// ---------------------------------------------------------------------------
__global__ __launch_bounds__(256, 4) void gemm_prep(
    const float* __restrict__ x, const float* __restrict__ W,
    const float* __restrict__ bias,
    const int* __restrict__ edge_dst, int* __restrict__ row_ptr,
    ushort* __restrict__ support) {
  const int tid  = threadIdx.x;
  const int bid  = blockIdx.x;

  if (bid >= GEMM_BLOCKS) {
    const int e = (bid - GEMM_BLOCKS) * 256 + tid;
    if (e < N_EDGES) {
      const int d = edge_dst[e];
      if (e == 0) {
        for (int n = 0; n <= d; ++n) row_ptr[n] = 0;
      } else {
        const int dp = edge_dst[e - 1];
        if (d != dp)
          for (int n = dp + 1; n <= d; ++n) row_ptr[n] = e;
      }
      if (e == N_EDGES - 1)
        for (int n = d + 1; n <= N_NODES; ++n) row_ptr[n] = N_EDGES;
    }
    return;
  }

  // ---- gemm (R13 body, frozen) ----
  __shared__ ushort Wl[D_OUT * D_IN];  // 32 KB, XOR-swizzled
  const int wave = tid >> 6;
  const int lane = tid & 63;
  const int m0  = bid * 64 + wave * 16;
  const int r16 = lane & 15;
  const int kg  = lane >> 4;
  int arow = m0 + r16;
  if (arow >= N_NODES) arow = N_NODES - 1;   // clamp; stores guarded
  const float* xp = x + (size_t)arow * D_IN + kg * 8;

  // wave's entire A-slice: 16 independent 16B loads, forced in flight.
  f32x4 xd[16];
  XLOAD(xd[0], 0);    XLOAD(xd[1], 16);
  XLOAD(xd[2], 128);  XLOAD(xd[3], 144);
  XLOAD(xd[4], 256);  XLOAD(xd[5], 272);
  XLOAD(xd[6], 384);  XLOAD(xd[7], 400);
  XLOAD(xd[8], 512);  XLOAD(xd[9], 528);
  XLOAD(xd[10], 640); XLOAD(xd[11], 656);
  XLOAD(xd[12], 768); XLOAD(xd[13], 784);
  XLOAD(xd[14], 896); XLOAD(xd[15], 912);

  // W -> LDS under the x-miss latency.
  for (int c = tid; c < (D_OUT * D_IN) / 8; c += 256) {
    const int row = c >> 5;
    const int cc  = c & 31;
    const f32x4 w0 = *reinterpret_cast<const f32x4*>(W + c * 8);
    const f32x4 w1 = *reinterpret_cast<const f32x4*>(W + c * 8 + 4);
    bf16x8 v;
    v[0] = (short)f2bf(w0[0]); v[1] = (short)f2bf(w0[1]);
    v[2] = (short)f2bf(w0[2]); v[3] = (short)f2bf(w0[3]);
    v[4] = (short)f2bf(w1[0]); v[5] = (short)f2bf(w1[1]);
    v[6] = (short)f2bf(w1[2]); v[7] = (short)f2bf(w1[3]);
    unsigned byte = row * 512 + cc * 16;
    byte ^= (row & 7) << 4;                 // st-swizzle (conflict-free b128)
    *reinterpret_cast<bf16x8*>(reinterpret_cast<char*>(Wl) + byte) = v;
  }
  __syncthreads();

  // drain asm loads; fence consumers (rule #18).
  asm volatile("s_waitcnt vmcnt(0)" ::: "memory");
  __builtin_amdgcn_sched_barrier(0);

  // consume: convert + MFMA.
  f32x4 acc[4] = {f32x4{0.f,0.f,0.f,0.f}, f32x4{0.f,0.f,0.f,0.f},
                  f32x4{0.f,0.f,0.f,0.f}, f32x4{0.f,0.f,0.f,0.f}};
#pragma unroll
  for (int ks = 0; ks < 8; ++ks) {
    const f32x4 xa = xd[2 * ks];
    const f32x4 xb = xd[2 * ks + 1];
    bf16x8 a;
    a[0] = (short)f2bf(xa[0]); a[1] = (short)f2bf(xa[1]);
    a[2] = (short)f2bf(xa[2]); a[3] = (short)f2bf(xa[3]);
    a[4] = (short)f2bf(xb[0]); a[5] = (short)f2bf(xb[1]);
    a[6] = (short)f2bf(xb[2]); a[7] = (short)f2bf(xb[3]);
#pragma unroll
    for (int nb = 0; nb < 4; ++nb) {
      const int row = nb * 16 + r16;
      unsigned byte = row * 512 + kg * 16 + ks * 64;   // same lane->k map as A
      byte ^= (row & 7) << 4;                          // ld-swizzle
      const bf16x8 bfrag = *reinterpret_cast<const bf16x8*>(
          reinterpret_cast<const char*>(Wl) + byte);
      acc[nb] =
          __builtin_amdgcn_mfma_f32_16x16x32_bf16(a, bfrag, acc[nb], 0, 0, 0);
    }
  }
#pragma unroll
  for (int nb = 0; nb < 4; ++nb) {
    const int col = nb * 16 + r16;
    const float bv = bias[col];
#pragma unroll
    for (int i = 0; i < 4; ++i) {
      const int row = m0 + kg * 4 + i;  // C/D: col=lane&15, row=(lane>>4)*4+reg
      if (row < N_NODES)
        support[(size_t)row * D_OUT + col] = f2bf(acc[nb][i] + bv);
    }
  }
}

// ---------------------------------------------------------------------------
// Aggregation + LeakyReLU — QUAD-NODE WAVES, 4-deep (this round).
// R20 proved the chain-ILP/balance mechanism (+1.2us at 2 nodes). Now 4
// adjacent nodes per wave {4w..4w+3} (N%4==0: all exist, no guards):
//  * 5 row_ptr bounds, shared boundaries
//  * main loop: one 4-edge block per node while ALL have >=4 left ->
//    16 gathers in flight across 4 independent chains; per-wave work
//    ~ Poisson(64) -> tail variance halves again; 12.5K waves.
//  * per-node 4-deep drains, wave-uniform branches, NO per-lane clamps
//    (the R17 spill came from clamp temps at 8-deep).
// (256,4): 128-VGPR cap; ~70 live VGPRs cannot spill. Chains/CU 48 -> 64.
// ---------------------------------------------------------------------------
__global__ __launch_bounds__(256, 4) void agg_kernel(
    const ushort* __restrict__ support, const int* __restrict__ edge_src,
    const float* __restrict__ edge_val, const int* __restrict__ row_ptr,
    float* __restrict__ out) {
  const int wq = (blockIdx.x * 256 + threadIdx.x) >> 6;   // node-quad id
  const int lane = threadIdx.x & 63;
  if (wq >= N_NODES / 4) return;
  const int n0 = wq * 4;
  const int b0 = row_ptr[n0];
  const int b1 = row_ptr[n0 + 1];
  const int b2 = row_ptr[n0 + 2];
  const int b3 = row_ptr[n0 + 3];
  const int b4 = row_ptr[n0 + 4];

  int eA = b0, eB = b1, eC = b2, eD = b3;
  float aA[4] = {0.f, 0.f, 0.f, 0.f};
  float aB[4] = {0.f, 0.f, 0.f, 0.f};
  float aC[4] = {0.f, 0.f, 0.f, 0.f};
  float aD[4] = {0.f, 0.f, 0.f, 0.f};

  // main loop: one 4-edge block per node while all four have >=4 remaining.
  while (eA + 4 <= b1 && eB + 4 <= b2 && eC + 4 <= b3 && eD + 4 <= b4) {
    i32x4 sA, sB, sC, sD;
    f32x4 vA, vB, vC, vD;
    __builtin_memcpy(&sA, edge_src + eA, 16);
    __builtin_memcpy(&vA, edge_val + eA, 16);
    __builtin_memcpy(&sB, edge_src + eB, 16);
    __builtin_memcpy(&vB, edge_val + eB, 16);
    __builtin_memcpy(&sC, edge_src + eC, 16);
    __builtin_memcpy(&vC, edge_val + eC, 16);
    __builtin_memcpy(&sD, edge_src + eD, 16);
    __builtin_memcpy(&vD, edge_val + eD, 16);
#pragma unroll
    for (int j = 0; j < 4; ++j)
      aA[j] = fmaf(vA[j], bf2f(support[(size_t)sA[j] * D_OUT + lane]), aA[j]);
#pragma unroll
    for (int j = 0; j < 4; ++j)
      aB[j] = fmaf(vB[j], bf2f(support[(size_t)sB[j] * D_OUT + lane]), aB[j]);
#pragma unroll
    for (int j = 0; j < 4; ++j)
      aC[j] = fmaf(vC[j], bf2f(support[(size_t)sC[j] * D_OUT + lane]), aC[j]);
#pragma unroll
    for (int j = 0; j < 4; ++j)
      aD[j] = fmaf(vD[j], bf2f(support[(size_t)sD[j] * D_OUT + lane]), aD[j]);
    eA += 4; eB += 4; eC += 4; eD += 4;
  }

  // per-node drains (wave-uniform branches, 4-deep then scalar).
#define DRAIN(eX, hiX, aX)                                                   \
  for (; eX + 4 <= hiX; eX += 4) {                                           \
    i32x4 s4; f32x4 v4;                                                      \
    __builtin_memcpy(&s4, edge_src + eX, 16);                                \
    __builtin_memcpy(&v4, edge_val + eX, 16);                                \
    _Pragma("unroll")                                                        \
    for (int j = 0; j < 4; ++j)                                              \
      aX[j] = fmaf(v4[j], bf2f(support[(size_t)s4[j] * D_OUT + lane]), aX[j]);\
  }                                                                          \
  for (; eX < hiX; ++eX)                                                     \
    aX[0] = fmaf(edge_val[eX],                                               \
                 bf2f(support[(size_t)edge_src[eX] * D_OUT + lane]), aX[0]);

  DRAIN(eA, b1, aA)
  DRAIN(eB, b2, aB)
  DRAIN(eC, b3, aC)
  DRAIN(eD, b4, aD)
#undef DRAIN

  const float rA = (aA[0] + aA[1]) + (aA[2] + aA[3]);
  out[(size_t)n0 * D_OUT + lane] = rA >= 0.f ? rA : NEG_SLOPE * rA;
  const float rB = (aB[0] + aB[1]) + (aB[2] + aB[3]);
  out[(size_t)(n0 + 1) * D_OUT + lane] = rB >= 0.f ? rB : NEG_SLOPE * rB;
  const float rC = (aC[0] + aC[1]) + (aC[2] + aC[3]);
  out[(size_t)(n0 + 2) * D_OUT + lane] = rC >= 0.f ? rC : NEG_SLOPE * rC;
  const float rD = (aD[0] + aD[1]) + (aD[2] + aD[3]);
  out[(size_t)(n0 + 3) * D_OUT + lane] = rD >= 0.f ? rD : NEG_SLOPE * rD;
}

// ---------------------------------------------------------------------------
extern "C" void kernel_launch(void* const* d_in, const int* in_sizes, int n_in,
                              void* d_out, int out_size, void* d_ws, size_t ws_size,
                              hipStream_t stream) {
  const float* x        = (const float*)d_in[0];
  const float* W        = (const float*)d_in[1];
  const float* b        = (const float*)d_in[2];
  const int*   edge_src = (const int*)d_in[3];
  const int*   edge_dst = (const int*)d_in[4];
  const float* edge_val = (const float*)d_in[5];
  float* out = (float*)d_out;

  // workspace layout (R13)
  ushort* support = (ushort*)d_ws;                                  // 6.4 MB
  char* p = (char*)d_ws + (size_t)N_NODES * D_OUT * sizeof(ushort);
  int* row_ptr = (int*)p;                                           // 200 KB

  hipLaunchKernelGGL(gemm_prep, dim3(GRID1), dim3(256), 0, stream,
                     x, W, b, edge_dst, row_ptr, support);
  // 12500 node-quad waves -> 3125 blocks
  hipLaunchKernelGGL(agg_kernel, dim3((N_NODES / 4 * 64 + 255) / 256),
                     dim3(256), 0, stream,
                     support, edge_src, edge_val, row_ptr, out);
}

// Round 22
// 50.434 us; speedup vs baseline: 1.0529x; 1.0529x over previous
//
#include <hip/hip_runtime.h>

#define N_NODES 50000
#define N_EDGES 800000
#define D_IN 256
#define D_OUT 64
#define NEG_SLOPE 0.2f

#define GEMM_BLOCKS 782    // ceil(50000/64); 782*1024 >= 800000 edges for prep

typedef __attribute__((ext_vector_type(8))) short bf16x8;   // 8 bf16 = 4 VGPR
typedef __attribute__((ext_vector_type(4))) float f32x4;    // MFMA C/D
typedef __attribute__((ext_vector_type(4))) int   i32x4;

__device__ inline ushort f2bf(float f) {  // f32 -> bf16, round-nearest-even
  union { float f; unsigned u; } v; v.f = f;
  unsigned r = v.u + 0x7FFFu + ((v.u >> 16) & 1u);
  return (ushort)(r >> 16);
}
__device__ inline float bf2f(ushort h) {
  union { unsigned u; float f; } v; v.u = ((unsigned)h) << 16;
  return v.f;
}

// Issue one 16B global load via asm volatile (R12, kept).
#define XLOAD(dst, off)                                                  \
  asm volatile("global_load_dwordx4 %0, %1, off offset:" #off            \
               : "=v"(dst) : "v"(xp) : "memory")

// ---------------------------------------------------------------------------
// Kernel 1: 782 blocks, R13 gemm body + prep folded in AFTER the epilogue
// (this round's single change). R18's appended 3125 prep blocks still
// allocated the kernel's static 32KB LDS on their early-return path -> they
// ran as a multi-µs serialized tail. R19 folded prep in but BEFORE the
// barrier (critical-path penalty) and was confounded with an agg change.
// Here: prep's 4 edges/thread execute after the C-write, off every critical
// path; row_ptr is complete at kernel end (consumed only by dispatch 2).
// ---------------------------------------------------------------------------
__global__ __launch_bounds__(256, 4) void gemm_prep(
    const float* __restrict__ x, const float* __restrict__ W,
    const float* __restrict__ bias,
    const int* __restrict__ edge_dst, int* __restrict__ row_ptr,
    ushort* __restrict__ support) {
  const int tid  = threadIdx.x;
  const int bid  = blockIdx.x;

  __shared__ ushort Wl[D_OUT * D_IN];  // 32 KB, XOR-swizzled
  const int wave = tid >> 6;
  const int lane = tid & 63;
  const int m0  = bid * 64 + wave * 16;
  const int r16 = lane & 15;
  const int kg  = lane >> 4;
  int arow = m0 + r16;
  if (arow >= N_NODES) arow = N_NODES - 1;   // clamp; stores guarded
  const float* xp = x + (size_t)arow * D_IN + kg * 8;

  // (1) wave's entire A-slice: 16 independent 16B loads, forced in flight.
  f32x4 xd[16];
  XLOAD(xd[0], 0);    XLOAD(xd[1], 16);
  XLOAD(xd[2], 128);  XLOAD(xd[3], 144);
  XLOAD(xd[4], 256);  XLOAD(xd[5], 272);
  XLOAD(xd[6], 384);  XLOAD(xd[7], 400);
  XLOAD(xd[8], 512);  XLOAD(xd[9], 528);
  XLOAD(xd[10], 640); XLOAD(xd[11], 656);
  XLOAD(xd[12], 768); XLOAD(xd[13], 784);
  XLOAD(xd[14], 896); XLOAD(xd[15], 912);

  // (2) W -> LDS under the x-miss latency.
  for (int c = tid; c < (D_OUT * D_IN) / 8; c += 256) {
    const int row = c >> 5;
    const int cc  = c & 31;
    const f32x4 w0 = *reinterpret_cast<const f32x4*>(W + c * 8);
    const f32x4 w1 = *reinterpret_cast<const f32x4*>(W + c * 8 + 4);
    bf16x8 v;
    v[0] = (short)f2bf(w0[0]); v[1] = (short)f2bf(w0[1]);
    v[2] = (short)f2bf(w0[2]); v[3] = (short)f2bf(w0[3]);
    v[4] = (short)f2bf(w1[0]); v[5] = (short)f2bf(w1[1]);
    v[6] = (short)f2bf(w1[2]); v[7] = (short)f2bf(w1[3]);
    unsigned byte = row * 512 + cc * 16;
    byte ^= (row & 7) << 4;                 // st-swizzle (conflict-free b128)
    *reinterpret_cast<bf16x8*>(reinterpret_cast<char*>(Wl) + byte) = v;
  }
  __syncthreads();

  // (3) drain asm loads; fence consumers (rule #18).
  asm volatile("s_waitcnt vmcnt(0)" ::: "memory");
  __builtin_amdgcn_sched_barrier(0);

  // (4) consume: convert + MFMA.
  f32x4 acc[4] = {f32x4{0.f,0.f,0.f,0.f}, f32x4{0.f,0.f,0.f,0.f},
                  f32x4{0.f,0.f,0.f,0.f}, f32x4{0.f,0.f,0.f,0.f}};
#pragma unroll
  for (int ks = 0; ks < 8; ++ks) {
    const f32x4 xa = xd[2 * ks];
    const f32x4 xb = xd[2 * ks + 1];
    bf16x8 a;
    a[0] = (short)f2bf(xa[0]); a[1] = (short)f2bf(xa[1]);
    a[2] = (short)f2bf(xa[2]); a[3] = (short)f2bf(xa[3]);
    a[4] = (short)f2bf(xb[0]); a[5] = (short)f2bf(xb[1]);
    a[6] = (short)f2bf(xb[2]); a[7] = (short)f2bf(xb[3]);
#pragma unroll
    for (int nb = 0; nb < 4; ++nb) {
      const int row = nb * 16 + r16;
      unsigned byte = row * 512 + kg * 16 + ks * 64;   // same lane->k map as A
      byte ^= (row & 7) << 4;                          // ld-swizzle
      const bf16x8 bfrag = *reinterpret_cast<const bf16x8*>(
          reinterpret_cast<const char*>(Wl) + byte);
      acc[nb] =
          __builtin_amdgcn_mfma_f32_16x16x32_bf16(a, bfrag, acc[nb], 0, 0, 0);
    }
  }
#pragma unroll
  for (int nb = 0; nb < 4; ++nb) {
    const int col = nb * 16 + r16;
    const float bv = bias[col];
#pragma unroll
    for (int i = 0; i < 4; ++i) {
      const int row = m0 + kg * 4 + i;  // C/D: col=lane&15, row=(lane>>4)*4+reg
      if (row < N_NODES)
        support[(size_t)row * D_OUT + col] = f2bf(acc[nb][i] + bv);
    }
  }

  // (5) prep: this block's 1024 edges (4/thread), AFTER the epilogue.
  {
    const int e0 = bid * 1024 + tid * 4;
    if (e0 < N_EDGES) {
      int d4[4];
      if (e0 + 3 < N_EDGES) {
        i32x4 t;
        __builtin_memcpy(&t, edge_dst + e0, 16);
        d4[0] = t[0]; d4[1] = t[1]; d4[2] = t[2]; d4[3] = t[3];
      } else {
#pragma unroll
        for (int j = 0; j < 4; ++j)
          d4[j] = (e0 + j < N_EDGES) ? edge_dst[e0 + j] : 0;
      }
      const int dprev = (e0 == 0) ? -1 : edge_dst[e0 - 1];
#pragma unroll
      for (int j = 0; j < 4; ++j) {
        const int e = e0 + j;
        if (e >= N_EDGES) break;
        const int d  = d4[j];
        const int dp = (j == 0) ? dprev : d4[j - 1];
        if (d != dp)
          for (int n = dp + 1; n <= d; ++n) row_ptr[n] = e;  // e==0 fills 0..d
        if (e == N_EDGES - 1)
          for (int n = d + 1; n <= N_NODES; ++n) row_ptr[n] = N_EDGES;
      }
    }
  }
}

// ---------------------------------------------------------------------------
// Aggregation + LeakyReLU — EXACT R20 (best: dual-node, 4-deep, no spills).
// ---------------------------------------------------------------------------
__global__ __launch_bounds__(256, 6) void agg_kernel(
    const ushort* __restrict__ support, const int* __restrict__ edge_src,
    const float* __restrict__ edge_val, const int* __restrict__ row_ptr,
    float* __restrict__ out) {
  const int wp = (blockIdx.x * 256 + threadIdx.x) >> 6;   // node-pair id
  const int lane = threadIdx.x & 63;
  if (wp >= N_NODES / 2) return;                           // N even: B exists
  const int nA = wp * 2;
  const int loA = row_ptr[nA];
  const int hiA = row_ptr[nA + 1];     // == loB (adjacent nodes)
  const int hiB = row_ptr[nA + 2];

  int eA = loA, eB = hiA;
  float aA[4] = {0.f, 0.f, 0.f, 0.f};
  float aB[4] = {0.f, 0.f, 0.f, 0.f};

  while (eA + 4 <= hiA && eB + 4 <= hiB) {
    i32x4 sA, sB;
    f32x4 vA, vB;
    __builtin_memcpy(&sA, edge_src + eA, 16);
    __builtin_memcpy(&vA, edge_val + eA, 16);
    __builtin_memcpy(&sB, edge_src + eB, 16);
    __builtin_memcpy(&vB, edge_val + eB, 16);
#pragma unroll
    for (int j = 0; j < 4; ++j)
      aA[j] = fmaf(vA[j], bf2f(support[(size_t)sA[j] * D_OUT + lane]), aA[j]);
#pragma unroll
    for (int j = 0; j < 4; ++j)
      aB[j] = fmaf(vB[j], bf2f(support[(size_t)sB[j] * D_OUT + lane]), aB[j]);
    eA += 4;
    eB += 4;
  }
  for (; eA + 4 <= hiA; eA += 4) {
    i32x4 s4; f32x4 v4;
    __builtin_memcpy(&s4, edge_src + eA, 16);
    __builtin_memcpy(&v4, edge_val + eA, 16);
#pragma unroll
    for (int j = 0; j < 4; ++j)
      aA[j] = fmaf(v4[j], bf2f(support[(size_t)s4[j] * D_OUT + lane]), aA[j]);
  }
  for (; eA < hiA; ++eA)
    aA[0] = fmaf(edge_val[eA],
                 bf2f(support[(size_t)edge_src[eA] * D_OUT + lane]), aA[0]);
  for (; eB + 4 <= hiB; eB += 4) {
    i32x4 s4; f32x4 v4;
    __builtin_memcpy(&s4, edge_src + eB, 16);
    __builtin_memcpy(&v4, edge_val + eB, 16);
#pragma unroll
    for (int j = 0; j < 4; ++j)
      aB[j] = fmaf(v4[j], bf2f(support[(size_t)s4[j] * D_OUT + lane]), aB[j]);
  }
  for (; eB < hiB; ++eB)
    aB[0] = fmaf(edge_val[eB],
                 bf2f(support[(size_t)edge_src[eB] * D_OUT + lane]), aB[0]);

  const float rA = (aA[0] + aA[1]) + (aA[2] + aA[3]);
  out[(size_t)nA * D_OUT + lane] = rA >= 0.f ? rA : NEG_SLOPE * rA;
  const float rB = (aB[0] + aB[1]) + (aB[2] + aB[3]);
  out[(size_t)(nA + 1) * D_OUT + lane] = rB >= 0.f ? rB : NEG_SLOPE * rB;
}

// ---------------------------------------------------------------------------
extern "C" void kernel_launch(void* const* d_in, const int* in_sizes, int n_in,
                              void* d_out, int out_size, void* d_ws, size_t ws_size,
                              hipStream_t stream) {
  const float* x        = (const float*)d_in[0];
  const float* W        = (const float*)d_in[1];
  const float* b        = (const float*)d_in[2];
  const int*   edge_src = (const int*)d_in[3];
  const int*   edge_dst = (const int*)d_in[4];
  const float* edge_val = (const float*)d_in[5];
  float* out = (float*)d_out;

  // workspace layout (R13)
  ushort* support = (ushort*)d_ws;                                  // 6.4 MB
  char* p = (char*)d_ws + (size_t)N_NODES * D_OUT * sizeof(ushort);
  int* row_ptr = (int*)p;                                           // 200 KB

  hipLaunchKernelGGL(gemm_prep, dim3(GEMM_BLOCKS), dim3(256), 0, stream,
                     x, W, b, edge_dst, row_ptr, support);
  // 25000 node-pair waves -> 6250 blocks
  hipLaunchKernelGGL(agg_kernel, dim3((N_NODES / 2 * 64 + 255) / 256),
                     dim3(256), 0, stream,
                     support, edge_src, edge_val, row_ptr, out);
}

// Round 23
// 49.167 us; speedup vs baseline: 1.0801x; 1.0258x over previous
//
#include <hip/hip_runtime.h>

#define N_NODES 50000
#define N_EDGES 800000
#define D_IN 256
#define D_OUT 64
#define NEG_SLOPE 0.2f

#define GEMM_BLOCKS 782    // ceil(50000/64) — dispatched FIRST (long poles)
#define PREP2_BLOCKS 3125  // ceil(800000/256) — 1 edge/thread, appended
#define GRID1 (GEMM_BLOCKS + PREP2_BLOCKS)

typedef __attribute__((ext_vector_type(8))) short bf16x8;   // 8 bf16 = 4 VGPR
typedef __attribute__((ext_vector_type(4))) float f32x4;    // MFMA C/D
typedef __attribute__((ext_vector_type(4))) int   i32x4;

__device__ inline ushort f2bf(float f) {  // f32 -> bf16, round-nearest-even
  union { float f; unsigned u; } v; v.f = f;
  unsigned r = v.u + 0x7FFFu + ((v.u >> 16) & 1u);
  return (ushort)(r >> 16);
}
__device__ inline float bf2f(ushort h) {
  union { unsigned u; float f; } v; v.u = ((unsigned)h) << 16;
  return v.f;
}

// Issue one 16B global load via asm volatile (R12, kept).
#define XLOAD(dst, off)                                                  \
  asm volatile("global_load_dwordx4 %0, %1, off offset:" #off            \
               : "=v"(dst) : "v"(xp) : "memory")

// ---------------------------------------------------------------------------
// Kernel 1 — R18/R20 exact. blocks <782 = one 16x64 MFMA tile per wave;
// blocks >=782 = CSR row_ptr, one edge per thread (no serial chains).
// ---------------------------------------------------------------------------
__global__ __launch_bounds__(256, 4) void gemm_prep(
    const float* __restrict__ x, const float* __restrict__ W,
    const float* __restrict__ bias,
    const int* __restrict__ edge_dst, int* __restrict__ row_ptr,
    ushort* __restrict__ support) {
  const int tid  = threadIdx.x;
  const int bid  = blockIdx.x;

  if (bid >= GEMM_BLOCKS) {
    const int e = (bid - GEMM_BLOCKS) * 256 + tid;
    if (e < N_EDGES) {
      const int d = edge_dst[e];
      if (e == 0) {
        for (int n = 0; n <= d; ++n) row_ptr[n] = 0;
      } else {
        const int dp = edge_dst[e - 1];
        if (d != dp)
          for (int n = dp + 1; n <= d; ++n) row_ptr[n] = e;
      }
      if (e == N_EDGES - 1)
        for (int n = d + 1; n <= N_NODES; ++n) row_ptr[n] = N_EDGES;
    }
    return;
  }

  // ---- gemm (R13 body, frozen) ----
  __shared__ ushort Wl[D_OUT * D_IN];  // 32 KB, XOR-swizzled
  const int wave = tid >> 6;
  const int lane = tid & 63;
  const int m0  = bid * 64 + wave * 16;
  const int r16 = lane & 15;
  const int kg  = lane >> 4;
  int arow = m0 + r16;
  if (arow >= N_NODES) arow = N_NODES - 1;   // clamp; stores guarded
  const float* xp = x + (size_t)arow * D_IN + kg * 8;

  // wave's entire A-slice: 16 independent 16B loads, forced in flight.
  f32x4 xd[16];
  XLOAD(xd[0], 0);    XLOAD(xd[1], 16);
  XLOAD(xd[2], 128);  XLOAD(xd[3], 144);
  XLOAD(xd[4], 256);  XLOAD(xd[5], 272);
  XLOAD(xd[6], 384);  XLOAD(xd[7], 400);
  XLOAD(xd[8], 512);  XLOAD(xd[9], 528);
  XLOAD(xd[10], 640); XLOAD(xd[11], 656);
  XLOAD(xd[12], 768); XLOAD(xd[13], 784);
  XLOAD(xd[14], 896); XLOAD(xd[15], 912);

  // W -> LDS under the x-miss latency.
  for (int c = tid; c < (D_OUT * D_IN) / 8; c += 256) {
    const int row = c >> 5;
    const int cc  = c & 31;
    const f32x4 w0 = *reinterpret_cast<const f32x4*>(W + c * 8);
    const f32x4 w1 = *reinterpret_cast<const f32x4*>(W + c * 8 + 4);
    bf16x8 v;
    v[0] = (short)f2bf(w0[0]); v[1] = (short)f2bf(w0[1]);
    v[2] = (short)f2bf(w0[2]); v[3] = (short)f2bf(w0[3]);
    v[4] = (short)f2bf(w1[0]); v[5] = (short)f2bf(w1[1]);
    v[6] = (short)f2bf(w1[2]); v[7] = (short)f2bf(w1[3]);
    unsigned byte = row * 512 + cc * 16;
    byte ^= (row & 7) << 4;                 // st-swizzle (conflict-free b128)
    *reinterpret_cast<bf16x8*>(reinterpret_cast<char*>(Wl) + byte) = v;
  }
  __syncthreads();

  // drain asm loads; fence consumers (rule #18).
  asm volatile("s_waitcnt vmcnt(0)" ::: "memory");
  __builtin_amdgcn_sched_barrier(0);

  // consume: convert + MFMA.
  f32x4 acc[4] = {f32x4{0.f,0.f,0.f,0.f}, f32x4{0.f,0.f,0.f,0.f},
                  f32x4{0.f,0.f,0.f,0.f}, f32x4{0.f,0.f,0.f,0.f}};
#pragma unroll
  for (int ks = 0; ks < 8; ++ks) {
    const f32x4 xa = xd[2 * ks];
    const f32x4 xb = xd[2 * ks + 1];
    bf16x8 a;
    a[0] = (short)f2bf(xa[0]); a[1] = (short)f2bf(xa[1]);
    a[2] = (short)f2bf(xa[2]); a[3] = (short)f2bf(xa[3]);
    a[4] = (short)f2bf(xb[0]); a[5] = (short)f2bf(xb[1]);
    a[6] = (short)f2bf(xb[2]); a[7] = (short)f2bf(xb[3]);
#pragma unroll
    for (int nb = 0; nb < 4; ++nb) {
      const int row = nb * 16 + r16;
      unsigned byte = row * 512 + kg * 16 + ks * 64;   // same lane->k map as A
      byte ^= (row & 7) << 4;                          // ld-swizzle
      const bf16x8 bfrag = *reinterpret_cast<const bf16x8*>(
          reinterpret_cast<const char*>(Wl) + byte);
      acc[nb] =
          __builtin_amdgcn_mfma_f32_16x16x32_bf16(a, bfrag, acc[nb], 0, 0, 0);
    }
  }
#pragma unroll
  for (int nb = 0; nb < 4; ++nb) {
    const int col = nb * 16 + r16;
    const float bv = bias[col];
#pragma unroll
    for (int i = 0; i < 4; ++i) {
      const int row = m0 + kg * 4 + i;  // C/D: col=lane&15, row=(lane>>4)*4+reg
      if (row < N_NODES)
        support[(size_t)row * D_OUT + col] = f2bf(acc[nb][i] + bv);
    }
  }
}

// ---------------------------------------------------------------------------
// Aggregation + LeakyReLU — R20 exact (best measured: dual-node, 4-deep,
// shared row_ptr boundary, no spills, (256,6)).
// ---------------------------------------------------------------------------
__global__ __launch_bounds__(256, 6) void agg_kernel(
    const ushort* __restrict__ support, const int* __restrict__ edge_src,
    const float* __restrict__ edge_val, const int* __restrict__ row_ptr,
    float* __restrict__ out) {
  const int wp = (blockIdx.x * 256 + threadIdx.x) >> 6;   // node-pair id
  const int lane = threadIdx.x & 63;
  if (wp >= N_NODES / 2) return;                           // N even: B exists
  const int nA = wp * 2;
  const int loA = row_ptr[nA];
  const int hiA = row_ptr[nA + 1];     // == loB (adjacent nodes)
  const int hiB = row_ptr[nA + 2];

  int eA = loA, eB = hiA;
  float aA[4] = {0.f, 0.f, 0.f, 0.f};
  float aB[4] = {0.f, 0.f, 0.f, 0.f};

  // interleaved main loop: one 4-edge block per node per iteration.
  while (eA + 4 <= hiA && eB + 4 <= hiB) {
    i32x4 sA, sB;
    f32x4 vA, vB;
    __builtin_memcpy(&sA, edge_src + eA, 16);
    __builtin_memcpy(&vA, edge_val + eA, 16);
    __builtin_memcpy(&sB, edge_src + eB, 16);
    __builtin_memcpy(&vB, edge_val + eB, 16);
#pragma unroll
    for (int j = 0; j < 4; ++j)
      aA[j] = fmaf(vA[j], bf2f(support[(size_t)sA[j] * D_OUT + lane]), aA[j]);
#pragma unroll
    for (int j = 0; j < 4; ++j)
      aB[j] = fmaf(vB[j], bf2f(support[(size_t)sB[j] * D_OUT + lane]), aB[j]);
    eA += 4;
    eB += 4;
  }
  // drain A
  for (; eA + 4 <= hiA; eA += 4) {
    i32x4 s4; f32x4 v4;
    __builtin_memcpy(&s4, edge_src + eA, 16);
    __builtin_memcpy(&v4, edge_val + eA, 16);
#pragma unroll
    for (int j = 0; j < 4; ++j)
      aA[j] = fmaf(v4[j], bf2f(support[(size_t)s4[j] * D_OUT + lane]), aA[j]);
  }
  for (; eA < hiA; ++eA)
    aA[0] = fmaf(edge_val[eA],
                 bf2f(support[(size_t)edge_src[eA] * D_OUT + lane]), aA[0]);
  // drain B
  for (; eB + 4 <= hiB; eB += 4) {
    i32x4 s4; f32x4 v4;
    __builtin_memcpy(&s4, edge_src + eB, 16);
    __builtin_memcpy(&v4, edge_val + eB, 16);
#pragma unroll
    for (int j = 0; j < 4; ++j)
      aB[j] = fmaf(v4[j], bf2f(support[(size_t)s4[j] * D_OUT + lane]), aB[j]);
  }
  for (; eB < hiB; ++eB)
    aB[0] = fmaf(edge_val[eB],
                 bf2f(support[(size_t)edge_src[eB] * D_OUT + lane]), aB[0]);

  const float rA = (aA[0] + aA[1]) + (aA[2] + aA[3]);
  out[(size_t)nA * D_OUT + lane] = rA >= 0.f ? rA : NEG_SLOPE * rA;
  const float rB = (aB[0] + aB[1]) + (aB[2] + aB[3]);
  out[(size_t)(nA + 1) * D_OUT + lane] = rB >= 0.f ? rB : NEG_SLOPE * rB;
}

// ---------------------------------------------------------------------------
extern "C" void kernel_launch(void* const* d_in, const int* in_sizes, int n_in,
                              void* d_out, int out_size, void* d_ws, size_t ws_size,
                              hipStream_t stream) {
  const float* x        = (const float*)d_in[0];
  const float* W        = (const float*)d_in[1];
  const float* b        = (const float*)d_in[2];
  const int*   edge_src = (const int*)d_in[3];
  const int*   edge_dst = (const int*)d_in[4];
  const float* edge_val = (const float*)d_in[5];
  float* out = (float*)d_out;

  // workspace layout (R13)
  ushort* support = (ushort*)d_ws;                                  // 6.4 MB
  char* p = (char*)d_ws + (size_t)N_NODES * D_OUT * sizeof(ushort);
  int* row_ptr = (int*)p;                                           // 200 KB

  hipLaunchKernelGGL(gemm_prep, dim3(GRID1), dim3(256), 0, stream,
                     x, W, b, edge_dst, row_ptr, support);
  // 25000 node-pair waves -> 6250 blocks
  hipLaunchKernelGGL(agg_kernel, dim3((N_NODES / 2 * 64 + 255) / 256),
                     dim3(256), 0, stream,
                     support, edge_src, edge_val, row_ptr, out);
}